// Round 11
// baseline (330.242 us; speedup 1.0000x reference)
//
#include <hip/hip_runtime.h>
#include <hip/hip_bf16.h>

#define IN_C 512
#define HID 64
#define OP_C 64
#define OUT_C 2

#define NPB 256          // nodes per bucket
#define NPB_SHIFT 8
#define MAXB 512         // max buckets (N <= 131072)
#define BINB 1024        // binning block size
#define EPT 8            // edges per thread in binning
#define EPB (BINB*EPT)   // 8192 edges per binning block
#define WFIX 16777216.0f // 2^24 fixed-point scale for weight sums

using bf16x8 = __attribute__((ext_vector_type(8))) short;
using f32x4  = __attribute__((ext_vector_type(4))) float;

static __device__ __forceinline__ unsigned short f2bf(float f) {
    unsigned int u = __float_as_uint(f);
    u = (u + 0x7FFFu + ((u >> 16) & 1u)) >> 16;   // RNE
    return (unsigned short)u;
}
static __device__ __forceinline__ short f2bf_hw(float f) {
    __bf16 h = (__bf16)f;                          // RNE; compiler pairs into v_cvt_pk_bf16_f32
    return __builtin_bit_cast(short, h);
}
static __device__ __forceinline__ float bf2f(unsigned short s) {
    return __uint_as_float(((unsigned int)s) << 16);
}

// pack: low32 = w fp32 bits; [48:32] = src (17b); [56:49] = lc (8b)
static __device__ __forceinline__ unsigned long long pack_e(int src, int lc, float w) {
    return ((unsigned long long)lc << 49) | ((unsigned long long)(unsigned)src << 32)
         | (unsigned long long)__float_as_uint(w);
}

// wprep helper: pack W (K x 64 fp32) into MFMA B-fragment order
static __device__ __forceinline__ void wprep_one(const float* __restrict__ W,
                                                 unsigned short* __restrict__ wfrag, int idx) {
    int e  = idx & 7;
    int l  = (idx >> 3) & 63;
    int nf = (idx >> 9) & 3;
    int kt = idx >> 11;
    int k  = kt * 32 + (l >> 4) * 8 + e;
    int c  = nf * 16 + (l & 15);
    wfrag[idx] = f2bf(W[k * 64 + c]);
}

// ---------------- fused setup: prem + wprep(W1) + wprep(W2) + zero gcnt ------
__global__ __launch_bounds__(256) void setup_k(const float* __restrict__ Wp,
                                               const float* __restrict__ bp,
                                               const float* __restrict__ Wfc,
                                               const float* __restrict__ bfc,
                                               float* M, float* cvec,
                                               const float* __restrict__ W1,
                                               unsigned short* __restrict__ wfrag1,
                                               const float* __restrict__ W2,
                                               unsigned short* __restrict__ wfrag2,
                                               int* gcnt, int B) {
    int b = blockIdx.x, t = threadIdx.x;
    if (b == 0) {
        if (t < 128) {
            int k = t >> 1, j = t & 1;
            float s = 0.f;
            for (int f = 0; f < IN_C; ++f) s += Wp[k * IN_C + f] * Wfc[f * 2 + j];
            M[t] = s;
        } else if (t < 130) {
            int j = t - 128;
            float s = bfc[j];
            for (int f = 0; f < IN_C; ++f) s += bp[f] * Wfc[f * 2 + j];
            cvec[j] = s;
        }
    } else if (b <= 128) {
        wprep_one(W1, wfrag1, (b - 1) * 256 + t);          // 512*64 = 32768
    } else if (b <= 144) {
        wprep_one(W2, wfrag2, (b - 129) * 256 + t);        // 64*64 = 4096
    } else {
        int i = (b - 145) * 256 + t;
        if (i < B) gcnt[i] = 0;
    }
}

// ---------------- P1a: per-block histogram + space reservation ----------------
__global__ __launch_bounds__(BINB) void p1a_k(const int* __restrict__ col,
                                              int* __restrict__ gcnt,
                                              int* __restrict__ blk_off,
                                              int E, int B) {
    __shared__ int hist[MAXB];
    int tid = threadIdx.x;
    long e0 = (long)blockIdx.x * EPB;
    for (int i = tid; i < B; i += BINB) hist[i] = 0;
    __syncthreads();
    #pragma unroll
    for (int j = 0; j < EPT; ++j) {
        long e = e0 + j * BINB + tid;
        if (e < E) atomicAdd(&hist[col[e] >> NPB_SHIFT], 1);
    }
    __syncthreads();
    for (int b = tid; b < B; b += BINB) {
        int h = hist[b];
        if (h > 0) blk_off[(long)blockIdx.x * B + b] = atomicAdd(&gcnt[b], h);
    }
}

// ---------------- P1b: per-block gcnt scan + LDS-sort + coalesced flush ------
__global__ __launch_bounds__(BINB) void p1b_k(const int* __restrict__ row,
                                              const int* __restrict__ col,
                                              const float* __restrict__ attr,
                                              const int* __restrict__ blk_off,
                                              const int* __restrict__ gcnt,
                                              int* __restrict__ bptr_out,
                                              unsigned long long* __restrict__ binned,
                                              int E, int B) {
    __shared__ int gbase[MAXB];      // global run base per bucket for this block
    __shared__ int loc[MAXB];        // hist -> exclusive local offsets
    __shared__ int scanb[512];
    __shared__ unsigned long long stage[EPB];   // 64KB sorted staging
    int tid = threadIdx.x;
    int blk = blockIdx.x;
    long e0 = (long)blk * EPB;
    // ---- scan gcnt -> exclusive global bucket offsets (bptr) ----
    int gval = (tid < B) ? gcnt[tid] : 0;
    if (tid < 512) scanb[tid] = gval;
    __syncthreads();
    for (int off = 1; off < 512; off <<= 1) {
        int y = 0;
        if (tid < 512 && tid >= off) y = scanb[tid - off];
        __syncthreads();
        if (tid < 512) scanb[tid] += y;
        __syncthreads();
    }
    if (tid < B) {
        int excl = scanb[tid] - gval;
        gbase[tid] = excl + blk_off[(long)blk * B + tid];
        loc[tid] = 0;
        if (blk == 0) bptr_out[tid] = excl;
    }
    if (blk == 0 && tid == 0) bptr_out[B] = E;
    __syncthreads();
    // ---- bin edges, rank within (block,bucket) ----
    unsigned long long pk[EPT]; int eb[EPT]; int er[EPT];
    #pragma unroll
    for (int j = 0; j < EPT; ++j) {
        long e = e0 + j * BINB + tid;
        eb[j] = -1;
        if (e < E) {
            int c = col[e];
            int b = c >> NPB_SHIFT;
            float w = 1.0f / (attr[e] + 1.0f);
            pk[j] = pack_e(row[e], c & (NPB - 1), w);
            eb[j] = b;
            er[j] = atomicAdd(&loc[b], 1);
        }
    }
    __syncthreads();
    // ---- exclusive scan of loc[0..B) ----
    if (tid < 512) scanb[tid] = (tid < B) ? loc[tid] : 0;
    __syncthreads();
    for (int off = 1; off < 512; off <<= 1) {
        int y = 0;
        if (tid < 512 && tid >= off) y = scanb[tid - off];
        __syncthreads();
        if (tid < 512) scanb[tid] += y;
        __syncthreads();
    }
    if (tid < B) loc[tid] = scanb[tid] - loc[tid];
    __syncthreads();
    // ---- scatter into sorted LDS staging ----
    #pragma unroll
    for (int j = 0; j < EPT; ++j)
        if (eb[j] >= 0) stage[loc[eb[j]] + er[j]] = pk[j];
    __syncthreads();
    // ---- flush ascending: consecutive lanes -> consecutive slots of a run ----
    long rem = E - e0;
    int ecnt = rem > EPB ? EPB : (int)rem;
    for (int i = tid; i < ecnt; i += BINB) {
        int lo = 0, hi = B - 1;
        #pragma unroll 1
        while (lo < hi) {
            int mid = (lo + hi + 1) >> 1;
            if (loc[mid] <= i) lo = mid; else hi = mid - 1;
        }
        binned[gbase[lo] + (i - loc[lo])] = stage[i];
    }
}

// ---------------- P2: per-bucket exact CSR build (block owns bucket) ---------
// packed LDS counter: [63:40] = count, [39:0] = sum(w * 2^24)
__global__ __launch_bounds__(256) void p2_k(const unsigned long long* __restrict__ binned,
                                            const int* __restrict__ bptr,
                                            int2* __restrict__ edges,
                                            int* __restrict__ rowptr,
                                            float* __restrict__ dinv,
                                            int N, int E) {
    __shared__ unsigned long long cf[NPB];
    __shared__ int excl[NPB];
    __shared__ int cur[NPB];
    __shared__ float dvl[NPB];
    int tid = threadIdx.x;
    int b = blockIdx.x;
    int e0 = bptr[b], e1 = bptr[b + 1];
    int c0 = b << NPB_SHIFT;
    cf[tid] = 0; cur[tid] = 0;
    if (b == 0 && tid == 0) rowptr[N] = E;
    __syncthreads();
    for (int i = e0 + tid; i < e1; i += 256) {
        unsigned long long p = binned[i];
        int lc = (int)(p >> 49);
        float w = __uint_as_float((unsigned int)p);
        unsigned long long add = (1ULL << 40) | (unsigned long long)(unsigned int)(w * WFIX);
        atomicAdd(&cf[lc], add);
    }
    __syncthreads();
    int cnt_t = (int)(cf[tid] >> 40);
    excl[tid] = cnt_t;
    __syncthreads();
    for (int off = 1; off < NPB; off <<= 1) {
        int v = (tid >= off) ? excl[tid - off] : 0;
        __syncthreads();
        excl[tid] += v;
        __syncthreads();
    }
    {
        int ex = excl[tid] - cnt_t;   // inclusive -> exclusive
        excl[tid] = ex;
        int c = c0 + tid;
        if (c < N) {
            rowptr[c] = e0 + ex;
            double fsum = (double)(cf[tid] & ((1ULL << 40) - 1));
            float deg = 1.0f + (float)(fsum * (1.0 / 16777216.0));
            float dv = rsqrtf(deg);
            dinv[c] = dv;
            dvl[tid] = dv;
        }
    }
    __syncthreads();
    for (int i = e0 + tid; i < e1; i += 256) {
        unsigned long long p = binned[i];
        int lc = (int)(p >> 49);
        int src = (int)((p >> 32) & 0x1FFFF);
        float w = __uint_as_float((unsigned int)p);
        int r = atomicAdd(&cur[lc], 1);
        float nrm_p = w * dvl[lc];  // w*dinv[col]; dinv[src] pre-folded into h2
        edges[e0 + excl[lc] + r] = make_int2(src, __float_as_int(nrm_p));
    }
}

// ---------------- MFMA gemm1: h2[M,64] = bf16( dinv * (bf16(x) @ W1frag) ) ---
__global__ __launch_bounds__(512) void gemm1_k(const float* __restrict__ A,
                                               const unsigned short* __restrict__ wfrag,
                                               const float* __restrict__ dinv,
                                               unsigned short* __restrict__ out, int M) {
    __shared__ unsigned short wlds[32768];   // 64KB: 16 kt * 4 nf * 64 lane * 8 e
    int tid = threadIdx.x;
    {
        const float4* s4 = (const float4*)wfrag;
        float4* d4 = (float4*)wlds;
        #pragma unroll
        for (int i = 0; i < 8; ++i) d4[tid + 512 * i] = s4[tid + 512 * i];
    }
    __syncthreads();
    int wv = tid >> 6, l = tid & 63;
    int lg = l >> 4, lr = l & 15;
    long band = (long)blockIdx.x * 128 + wv * 16;
    long row = band + lr;
    long rowc = row < M ? row : (long)(M - 1);
    const float* xp = A + rowc * IN_C + lg * 8;
    f32x4 acc0 = {0.f,0.f,0.f,0.f}, acc1 = {0.f,0.f,0.f,0.f};
    f32x4 acc2 = {0.f,0.f,0.f,0.f}, acc3 = {0.f,0.f,0.f,0.f};
    #pragma unroll 4
    for (int kt = 0; kt < 16; ++kt) {
        float4 xa = *(const float4*)(xp + kt * 32);
        float4 xb = *(const float4*)(xp + kt * 32 + 4);
        bf16x8 a;
        a[0] = f2bf_hw(xa.x); a[1] = f2bf_hw(xa.y);
        a[2] = f2bf_hw(xa.z); a[3] = f2bf_hw(xa.w);
        a[4] = f2bf_hw(xb.x); a[5] = f2bf_hw(xb.y);
        a[6] = f2bf_hw(xb.z); a[7] = f2bf_hw(xb.w);
        const bf16x8* bp = (const bf16x8*)&wlds[kt * 4 * 64 * 8 + l * 8];
        acc0 = __builtin_amdgcn_mfma_f32_16x16x32_bf16(a, bp[0],   acc0, 0, 0, 0);
        acc1 = __builtin_amdgcn_mfma_f32_16x16x32_bf16(a, bp[64],  acc1, 0, 0, 0);
        acc2 = __builtin_amdgcn_mfma_f32_16x16x32_bf16(a, bp[128], acc2, 0, 0, 0);
        acc3 = __builtin_amdgcn_mfma_f32_16x16x32_bf16(a, bp[192], acc3, 0, 0, 0);
    }
    #pragma unroll
    for (int r = 0; r < 4; ++r) {
        long orow = band + lg * 4 + r;
        if (orow < M) {
            float dv = dinv[orow];
            out[orow * 64 +  0 + lr] = f2bf(acc0[r] * dv);
            out[orow * 64 + 16 + lr] = f2bf(acc1[r] * dv);
            out[orow * 64 + 32 + lr] = f2bf(acc2[r] * dv);
            out[orow * 64 + 48 + lr] = f2bf(acc3[r] * dv);
        }
    }
}

// ---------------- fused aggmm: h2out = bf16(dinv * (relu(agg(h2)+b1) @ W2)) --
__global__ __launch_bounds__(256) void aggmm_k(const unsigned short* __restrict__ h2,
                                               const unsigned short* __restrict__ wfrag2,
                                               unsigned short* __restrict__ hout,
                                               const int* __restrict__ rowptr,
                                               const int2* __restrict__ edges,
                                               const float* __restrict__ dinv,
                                               const float* __restrict__ bias, int N) {
    __shared__ unsigned short glds[16 * 64];
    int tid = threadIdx.x;
    int w = tid >> 6, l = tid & 63;
    int q = l >> 4, r = l & 15;
    int node = blockIdx.x * 16 + w * 4 + q;
    float a0 = 0.f, a1 = 0.f, a2 = 0.f, a3 = 0.f;
    if (node < N) {
        float di = dinv[node];
        ushort4 hv = *(const ushort4*)(h2 + (size_t)node * 64 + 4 * r);
        a0 = di * bf2f(hv.x); a1 = di * bf2f(hv.y);
        a2 = di * bf2f(hv.z); a3 = di * bf2f(hv.w);
        int s = rowptr[node], e = rowptr[node + 1];
        for (int base = s; base < e; base += 16) {
            int mm = e - base; mm = mm > 16 ? 16 : mm;
            int2 my = edges[base + (r < mm ? r : 0)];
            if (mm == 16) {
                #pragma unroll
                for (int j = 0; j < 16; ++j) {
                    int srcj = __shfl(my.x, j, 16);
                    float nj = __int_as_float(__shfl(my.y, j, 16));
                    ushort4 qv = *(const ushort4*)(h2 + (size_t)srcj * 64 + 4 * r);
                    a0 += nj * bf2f(qv.x); a1 += nj * bf2f(qv.y);
                    a2 += nj * bf2f(qv.z); a3 += nj * bf2f(qv.w);
                }
            } else {
                for (int j = 0; j < mm; ++j) {
                    int srcj = __shfl(my.x, j, 16);
                    float nj = __int_as_float(__shfl(my.y, j, 16));
                    ushort4 qv = *(const ushort4*)(h2 + (size_t)srcj * 64 + 4 * r);
                    a0 += nj * bf2f(qv.x); a1 += nj * bf2f(qv.y);
                    a2 += nj * bf2f(qv.z); a3 += nj * bf2f(qv.w);
                }
            }
        }
        float4 bb = *(const float4*)(bias + 4 * r);
        a0 = fmaxf(a0 + bb.x, 0.f); a1 = fmaxf(a1 + bb.y, 0.f);
        a2 = fmaxf(a2 + bb.z, 0.f); a3 = fmaxf(a3 + bb.w, 0.f);
    }
    ushort4 gv; gv.x = f2bf(a0); gv.y = f2bf(a1); gv.z = f2bf(a2); gv.w = f2bf(a3);
    *(ushort4*)&glds[(w * 4 + q) * 64 + 4 * r] = gv;
    __syncthreads();
    // MFMA: wave w computes col-block nf = w (cols w*16 .. w*16+15)
    f32x4 acc = {0.f, 0.f, 0.f, 0.f};
    #pragma unroll
    for (int kt = 0; kt < 2; ++kt) {
        bf16x8 afrag = *(const bf16x8*)&glds[(l & 15) * 64 + kt * 32 + (l >> 4) * 8];
        bf16x8 bfrag = *(const bf16x8*)&wfrag2[(size_t)((kt * 4 + w) * 64 + l) * 8];
        acc = __builtin_amdgcn_mfma_f32_16x16x32_bf16(afrag, bfrag, acc, 0, 0, 0);
    }
    #pragma unroll
    for (int rr = 0; rr < 4; ++rr) {
        int nrow = blockIdx.x * 16 + (l >> 4) * 4 + rr;
        if (nrow < N) {
            float dv = dinv[nrow];
            hout[(size_t)nrow * 64 + w * 16 + (l & 15)] = f2bf(acc[rr] * dv);
        }
    }
}

// ---------------- agg2f: layer-2 agg + fused final projection ----------------
// half-wave per node; dual 16-edge chunks interleaved -> 32 gathers in flight
__device__ __forceinline__ void agg_core(const unsigned short* __restrict__ h2,
                                         const int* __restrict__ rowptr,
                                         const int2* __restrict__ edges,
                                         const float* __restrict__ dinv,
                                         const float* __restrict__ bias,
                                         int node, int l,
                                         float& acc0, float& acc1) {
    float di = dinv[node];
    ushort2 hv = *(const ushort2*)(h2 + (size_t)node * 64 + 2 * l);
    acc0 = di * bf2f(hv.x);        // self loop: dinv^2 * h = dinv * h2pre
    acc1 = di * bf2f(hv.y);
    int s = rowptr[node], e = rowptr[node + 1];
    int li = l & 15;
    int i = s;
    for (; i + 31 < e; i += 32) {
        int2 ma = edges[i + li];
        int2 mb = edges[i + 16 + li];
        #pragma unroll
        for (int j = 0; j < 16; ++j) {
            int sa = __shfl(ma.x, j, 32);
            float na = __int_as_float(__shfl(ma.y, j, 32));
            int sb = __shfl(mb.x, j, 32);
            float nb = __int_as_float(__shfl(mb.y, j, 32));
            ushort2 qa = *(const ushort2*)(h2 + (size_t)sa * 64 + 2 * l);
            ushort2 qb = *(const ushort2*)(h2 + (size_t)sb * 64 + 2 * l);
            acc0 += na * bf2f(qa.x) + nb * bf2f(qb.x);
            acc1 += na * bf2f(qa.y) + nb * bf2f(qb.y);
        }
    }
    for (; i < e; i += 16) {
        int mm = e - i; mm = mm > 16 ? 16 : mm;
        int2 my = edges[i + (li < mm ? li : 0)];
        if (mm == 16) {
            #pragma unroll
            for (int j = 0; j < 16; ++j) {
                int srcj = __shfl(my.x, j, 32);
                float nj = __int_as_float(__shfl(my.y, j, 32));
                ushort2 q = *(const ushort2*)(h2 + (size_t)srcj * 64 + 2 * l);
                acc0 += nj * bf2f(q.x);
                acc1 += nj * bf2f(q.y);
            }
        } else {
            for (int j = 0; j < mm; ++j) {
                int srcj = __shfl(my.x, j, 32);
                float nj = __int_as_float(__shfl(my.y, j, 32));
                ushort2 q = *(const ushort2*)(h2 + (size_t)srcj * 64 + 2 * l);
                acc0 += nj * bf2f(q.x);
                acc1 += nj * bf2f(q.y);
            }
        }
    }
    float2 bb = *(const float2*)(bias + 2 * l);
    acc0 = fmaxf(acc0 + bb.x, 0.0f);
    acc1 = fmaxf(acc1 + bb.y, 0.0f);
}

__global__ __launch_bounds__(256) void agg2f_k(const unsigned short* __restrict__ h2,
                                               const int* __restrict__ rowptr,
                                               const int2* __restrict__ edges,
                                               const float* __restrict__ dinv,
                                               const float* __restrict__ bias,
                                               const float* __restrict__ op,
                                               const float* __restrict__ M,
                                               const float* __restrict__ Wfc,
                                               const float* __restrict__ cvec,
                                               float* __restrict__ out, int N) {
    int wid = (blockIdx.x * 256 + threadIdx.x) >> 6;
    int lane = threadIdx.x & 63;
    int node = wid * 2 + (lane >> 5);
    int l = lane & 31;
    if (node >= N) return;
    float acc0, acc1;
    agg_core(h2, rowptr, edges, dinv, bias, node, l, acc0, acc1);
    float2 ov = *(const float2*)(op + (size_t)node * 64 + 2 * l);
    int f0 = 2 * l, f1 = 2 * l + 1;
    float p0 = acc0 * M[f0 * 2 + 0] + acc1 * M[f1 * 2 + 0]
             + ov.x * Wfc[(IN_C + f0) * 2 + 0] + ov.y * Wfc[(IN_C + f1) * 2 + 0];
    float p1 = acc0 * M[f0 * 2 + 1] + acc1 * M[f1 * 2 + 1]
             + ov.x * Wfc[(IN_C + f0) * 2 + 1] + ov.y * Wfc[(IN_C + f1) * 2 + 1];
    #pragma unroll
    for (int off = 16; off > 0; off >>= 1) {
        p0 += __shfl_xor(p0, off);
        p1 += __shfl_xor(p1, off);
    }
    if (l == 0)
        *(float2*)(out + (size_t)node * 2) = make_float2(p0 + cvec[0], p1 + cvec[1]);
}

extern "C" void kernel_launch(void* const* d_in, const int* in_sizes, int n_in,
                              void* d_out, int out_size, void* d_ws, size_t ws_size,
                              hipStream_t stream) {
    const float* x    = (const float*)d_in[0];
    const int*   ei   = (const int*)d_in[1];
    const float* attr = (const float*)d_in[2];
    const float* op   = (const float*)d_in[3];
    const float* W1   = (const float*)d_in[4];
    const float* b1   = (const float*)d_in[5];
    const float* W2   = (const float*)d_in[6];
    const float* b2   = (const float*)d_in[7];
    const float* Wp   = (const float*)d_in[8];
    const float* bp   = (const float*)d_in[9];
    const float* Wfc  = (const float*)d_in[10];
    const float* bfc  = (const float*)d_in[11];

    const int N = in_sizes[0] / IN_C;
    const int E = in_sizes[2];
    const int* row = ei;
    const int* col = ei + E;

    const int B     = (N + NPB - 1) >> NPB_SHIFT;
    const int nblk1 = (E + EPB - 1) / EPB;

    char* base = (char*)d_ws;
    size_t off = 0;
    auto alloc = [&](size_t bytes) -> char* {
        char* p = base + off;
        off = (off + bytes + 255) & ~(size_t)255;
        return p;
    };
    int2*  edges  = (int2*)alloc((size_t)E * 8);             // persistent CSR
    unsigned short* h2 = (unsigned short*)alloc((size_t)N * HID * 2); // layer-1 feats
    // region: binned u64 (E*8) dead after p2 -> later hout bf16 (N*64*2)
    size_t bin_b  = (size_t)E * 8;
    size_t g_b    = (size_t)N * HID * 2;
    char*  regC   = alloc(bin_b > g_b ? bin_b : g_b);
    unsigned long long* binned = (unsigned long long*)regC;
    unsigned short* hout = (unsigned short*)regC;
    int*   blkoff = (int*)alloc((size_t)nblk1 * B * 4);
    float* dinv   = (float*)alloc((size_t)N * 4);
    int*   rowptr = (int*)alloc((size_t)(N + 1) * 4);
    int*   gcnt   = (int*)alloc((size_t)MAXB * 4);
    int*   bptr   = (int*)alloc((size_t)(MAXB + 1) * 4);
    unsigned short* wfrag1 = (unsigned short*)alloc((size_t)IN_C * 64 * 2);  // 64KB
    unsigned short* wfrag2 = (unsigned short*)alloc((size_t)HID * 64 * 2);   // 8KB
    float* Mbuf   = (float*)alloc(512);
    float* cvec   = (float*)alloc(64);

    const int gAgg  = (((N + 1) / 2) * 64 + 255) / 256;
    const int gGemm = (N + 127) / 128;
    const int gAggmm = (N + 15) / 16;
    const int gSetup = 145 + (B + 255) / 256;

    setup_k<<<gSetup, 256, 0, stream>>>(Wp, bp, Wfc, bfc, Mbuf, cvec,
                                        W1, wfrag1, W2, wfrag2, gcnt, B);
    p1a_k<<<nblk1, BINB, 0, stream>>>(col, gcnt, blkoff, E, B);
    p1b_k<<<nblk1, BINB, 0, stream>>>(row, col, attr, blkoff, gcnt, bptr, binned, E, B);
    p2_k<<<B, 256, 0, stream>>>(binned, bptr, edges, rowptr, dinv, N, E);

    // conv1: h2 = bf16(dinv * (x @ W1)) via MFMA
    gemm1_k<<<gGemm, 512, 0, stream>>>(x, wfrag1, dinv, h2, N);
    // conv2 first half fused: hout = bf16(dinv * (relu(agg(h2)+b1) @ W2))
    aggmm_k<<<gAggmm, 256, 0, stream>>>(h2, wfrag2, hout, rowptr, edges, dinv, b1, N);
    // layer-2 agg + fused final projection
    agg2f_k<<<gAgg, 256, 0, stream>>>(hout, rowptr, edges, dinv, b2, op, Mbuf, Wfc, cvec,
                                      (float*)d_out, N);
}

// Round 12
// 284.025 us; speedup vs baseline: 1.1627x; 1.1627x over previous
//
#include <hip/hip_runtime.h>
#include <hip/hip_bf16.h>

#define IN_C 512
#define HID 64
#define OP_C 64
#define OUT_C 2

#define NPB 256          // nodes per bucket
#define NPB_SHIFT 8
#define MAXB 512         // max buckets (N <= 131072)
#define BINB 1024        // binning block size
#define EPT 8            // edges per thread in binning
#define EPB (BINB*EPT)   // 8192 edges per binning block
#define WFIX 16777216.0f // 2^24 fixed-point scale for weight sums

using bf16x8 = __attribute__((ext_vector_type(8))) short;
using f32x4  = __attribute__((ext_vector_type(4))) float;

static __device__ __forceinline__ unsigned short f2bf(float f) {
    unsigned int u = __float_as_uint(f);
    u = (u + 0x7FFFu + ((u >> 16) & 1u)) >> 16;   // RNE
    return (unsigned short)u;
}
static __device__ __forceinline__ short f2bf_hw(float f) {
    __bf16 h = (__bf16)f;                          // RNE; compiler pairs into v_cvt_pk_bf16_f32
    return __builtin_bit_cast(short, h);
}
static __device__ __forceinline__ float bf2f(unsigned short s) {
    return __uint_as_float(((unsigned int)s) << 16);
}

// pack: low32 = w fp32 bits; [48:32] = src (17b); [56:49] = lc (8b)
static __device__ __forceinline__ unsigned long long pack_e(int src, int lc, float w) {
    return ((unsigned long long)lc << 49) | ((unsigned long long)(unsigned)src << 32)
         | (unsigned long long)__float_as_uint(w);
}

// wprep helper: pack W (K x 64 fp32) into MFMA B-fragment order
static __device__ __forceinline__ void wprep_one(const float* __restrict__ W,
                                                 unsigned short* __restrict__ wfrag, int idx) {
    int e  = idx & 7;
    int l  = (idx >> 3) & 63;
    int nf = (idx >> 9) & 3;
    int kt = idx >> 11;
    int k  = kt * 32 + (l >> 4) * 8 + e;
    int c  = nf * 16 + (l & 15);
    wfrag[idx] = f2bf(W[k * 64 + c]);
}

// ---------------- fused setup: prem + wprep(W1) + wprep(W2) + zero gcnt ------
__global__ __launch_bounds__(256) void setup_k(const float* __restrict__ Wp,
                                               const float* __restrict__ bp,
                                               const float* __restrict__ Wfc,
                                               const float* __restrict__ bfc,
                                               float* M, float* cvec,
                                               const float* __restrict__ W1,
                                               unsigned short* __restrict__ wfrag1,
                                               const float* __restrict__ W2,
                                               unsigned short* __restrict__ wfrag2,
                                               int* gcnt, int B) {
    int b = blockIdx.x, t = threadIdx.x;
    if (b == 0) {
        if (t < 128) {
            int k = t >> 1, j = t & 1;
            float s = 0.f;
            for (int f = 0; f < IN_C; ++f) s += Wp[k * IN_C + f] * Wfc[f * 2 + j];
            M[t] = s;
        } else if (t < 130) {
            int j = t - 128;
            float s = bfc[j];
            for (int f = 0; f < IN_C; ++f) s += bp[f] * Wfc[f * 2 + j];
            cvec[j] = s;
        }
    } else if (b <= 128) {
        wprep_one(W1, wfrag1, (b - 1) * 256 + t);          // 512*64 = 32768
    } else if (b <= 144) {
        wprep_one(W2, wfrag2, (b - 129) * 256 + t);        // 64*64 = 4096
    } else {
        int i = (b - 145) * 256 + t;
        if (i < B) gcnt[i] = 0;
    }
}

// ---------------- P1a: per-block histogram + space reservation ----------------
__global__ __launch_bounds__(BINB) void p1a_k(const int* __restrict__ col,
                                              int* __restrict__ gcnt,
                                              int* __restrict__ blk_off,
                                              int E, int B) {
    __shared__ int hist[MAXB];
    int tid = threadIdx.x;
    long e0 = (long)blockIdx.x * EPB;
    for (int i = tid; i < B; i += BINB) hist[i] = 0;
    __syncthreads();
    #pragma unroll
    for (int j = 0; j < EPT; ++j) {
        long e = e0 + j * BINB + tid;
        if (e < E) atomicAdd(&hist[col[e] >> NPB_SHIFT], 1);
    }
    __syncthreads();
    for (int b = tid; b < B; b += BINB) {
        int h = hist[b];
        if (h > 0) blk_off[(long)blockIdx.x * B + b] = atomicAdd(&gcnt[b], h);
    }
}

// ---------------- P1b: per-block gcnt scan + LDS-sort + coalesced flush ------
__global__ __launch_bounds__(BINB) void p1b_k(const int* __restrict__ row,
                                              const int* __restrict__ col,
                                              const float* __restrict__ attr,
                                              const int* __restrict__ blk_off,
                                              const int* __restrict__ gcnt,
                                              int* __restrict__ bptr_out,
                                              unsigned long long* __restrict__ binned,
                                              int E, int B) {
    __shared__ int gbase[MAXB];      // global run base per bucket for this block
    __shared__ int loc[MAXB];        // hist -> exclusive local offsets
    __shared__ int scanb[512];
    __shared__ unsigned long long stage[EPB];   // 64KB sorted staging
    int tid = threadIdx.x;
    int blk = blockIdx.x;
    long e0 = (long)blk * EPB;
    // ---- scan gcnt -> exclusive global bucket offsets (bptr) ----
    int gval = (tid < B) ? gcnt[tid] : 0;
    if (tid < 512) scanb[tid] = gval;
    __syncthreads();
    for (int off = 1; off < 512; off <<= 1) {
        int y = 0;
        if (tid < 512 && tid >= off) y = scanb[tid - off];
        __syncthreads();
        if (tid < 512) scanb[tid] += y;
        __syncthreads();
    }
    if (tid < B) {
        int excl = scanb[tid] - gval;
        gbase[tid] = excl + blk_off[(long)blk * B + tid];
        loc[tid] = 0;
        if (blk == 0) bptr_out[tid] = excl;
    }
    if (blk == 0 && tid == 0) bptr_out[B] = E;
    __syncthreads();
    // ---- bin edges, rank within (block,bucket) ----
    unsigned long long pk[EPT]; int eb[EPT]; int er[EPT];
    #pragma unroll
    for (int j = 0; j < EPT; ++j) {
        long e = e0 + j * BINB + tid;
        eb[j] = -1;
        if (e < E) {
            int c = col[e];
            int b = c >> NPB_SHIFT;
            float w = 1.0f / (attr[e] + 1.0f);
            pk[j] = pack_e(row[e], c & (NPB - 1), w);
            eb[j] = b;
            er[j] = atomicAdd(&loc[b], 1);
        }
    }
    __syncthreads();
    // ---- exclusive scan of loc[0..B) ----
    if (tid < 512) scanb[tid] = (tid < B) ? loc[tid] : 0;
    __syncthreads();
    for (int off = 1; off < 512; off <<= 1) {
        int y = 0;
        if (tid < 512 && tid >= off) y = scanb[tid - off];
        __syncthreads();
        if (tid < 512) scanb[tid] += y;
        __syncthreads();
    }
    if (tid < B) loc[tid] = scanb[tid] - loc[tid];
    __syncthreads();
    // ---- scatter into sorted LDS staging ----
    #pragma unroll
    for (int j = 0; j < EPT; ++j)
        if (eb[j] >= 0) stage[loc[eb[j]] + er[j]] = pk[j];
    __syncthreads();
    // ---- flush ascending: consecutive lanes -> consecutive slots of a run ----
    long rem = E - e0;
    int ecnt = rem > EPB ? EPB : (int)rem;
    for (int i = tid; i < ecnt; i += BINB) {
        int lo = 0, hi = B - 1;
        #pragma unroll 1
        while (lo < hi) {
            int mid = (lo + hi + 1) >> 1;
            if (loc[mid] <= i) lo = mid; else hi = mid - 1;
        }
        binned[gbase[lo] + (i - loc[lo])] = stage[i];
    }
}

// ---------------- P2: per-bucket exact CSR build (block owns bucket) ---------
__global__ __launch_bounds__(256) void p2_k(const unsigned long long* __restrict__ binned,
                                            const int* __restrict__ bptr,
                                            int2* __restrict__ edges,
                                            int* __restrict__ rowptr,
                                            float* __restrict__ dinv,
                                            int N, int E) {
    __shared__ int cnt[NPB];
    __shared__ unsigned int fxw[NPB];
    __shared__ int excl[NPB];
    __shared__ int cur[NPB];
    __shared__ float dvl[NPB];
    int tid = threadIdx.x;
    int b = blockIdx.x;
    int e0 = bptr[b], e1 = bptr[b + 1];
    int c0 = b << NPB_SHIFT;
    cnt[tid] = 0; fxw[tid] = 0; cur[tid] = 0;
    if (b == 0 && tid == 0) rowptr[N] = E;
    __syncthreads();
    for (int i = e0 + tid; i < e1; i += 256) {
        unsigned long long p = binned[i];
        int lc = (int)(p >> 49);
        float w = __uint_as_float((unsigned int)p);
        atomicAdd(&cnt[lc], 1);
        atomicAdd(&fxw[lc], (unsigned int)(w * WFIX));
    }
    __syncthreads();
    excl[tid] = cnt[tid];
    __syncthreads();
    for (int off = 1; off < NPB; off <<= 1) {
        int v = (tid >= off) ? excl[tid - off] : 0;
        __syncthreads();
        excl[tid] += v;
        __syncthreads();
    }
    {
        int ex = excl[tid] - cnt[tid];   // inclusive -> exclusive
        excl[tid] = ex;
        int c = c0 + tid;
        if (c < N) {
            rowptr[c] = e0 + ex;
            float deg = 1.0f + (float)((double)fxw[tid] * (1.0 / 16777216.0));
            float dv = rsqrtf(deg);
            dinv[c] = dv;
            dvl[tid] = dv;
        }
    }
    __syncthreads();
    for (int i = e0 + tid; i < e1; i += 256) {
        unsigned long long p = binned[i];
        int lc = (int)(p >> 49);
        int src = (int)((p >> 32) & 0x1FFFF);
        float w = __uint_as_float((unsigned int)p);
        int r = atomicAdd(&cur[lc], 1);
        float nrm_p = w * dvl[lc];  // w*dinv[col]; dinv[src] pre-folded into h2
        edges[e0 + excl[lc] + r] = make_int2(src, __float_as_int(nrm_p));
    }
}

// ---------------- MFMA gemm1: h2[M,64] = bf16( dinv * (bf16(x) @ W1frag) ) ---
__global__ __launch_bounds__(512) void gemm1_k(const float* __restrict__ A,
                                               const unsigned short* __restrict__ wfrag,
                                               const float* __restrict__ dinv,
                                               unsigned short* __restrict__ out, int M) {
    __shared__ unsigned short wlds[32768];   // 64KB: 16 kt * 4 nf * 64 lane * 8 e
    int tid = threadIdx.x;
    {
        const float4* s4 = (const float4*)wfrag;
        float4* d4 = (float4*)wlds;
        #pragma unroll
        for (int i = 0; i < 8; ++i) d4[tid + 512 * i] = s4[tid + 512 * i];
    }
    __syncthreads();
    int wv = tid >> 6, l = tid & 63;
    int lg = l >> 4, lr = l & 15;
    long band = (long)blockIdx.x * 128 + wv * 16;
    long row = band + lr;
    long rowc = row < M ? row : (long)(M - 1);
    const float* xp = A + rowc * IN_C + lg * 8;
    f32x4 acc0 = {0.f,0.f,0.f,0.f}, acc1 = {0.f,0.f,0.f,0.f};
    f32x4 acc2 = {0.f,0.f,0.f,0.f}, acc3 = {0.f,0.f,0.f,0.f};
    #pragma unroll 4
    for (int kt = 0; kt < 16; ++kt) {
        float4 xa = *(const float4*)(xp + kt * 32);
        float4 xb = *(const float4*)(xp + kt * 32 + 4);
        bf16x8 a;
        a[0] = f2bf_hw(xa.x); a[1] = f2bf_hw(xa.y);
        a[2] = f2bf_hw(xa.z); a[3] = f2bf_hw(xa.w);
        a[4] = f2bf_hw(xb.x); a[5] = f2bf_hw(xb.y);
        a[6] = f2bf_hw(xb.z); a[7] = f2bf_hw(xb.w);
        const bf16x8* bp = (const bf16x8*)&wlds[kt * 4 * 64 * 8 + l * 8];
        acc0 = __builtin_amdgcn_mfma_f32_16x16x32_bf16(a, bp[0],   acc0, 0, 0, 0);
        acc1 = __builtin_amdgcn_mfma_f32_16x16x32_bf16(a, bp[64],  acc1, 0, 0, 0);
        acc2 = __builtin_amdgcn_mfma_f32_16x16x32_bf16(a, bp[128], acc2, 0, 0, 0);
        acc3 = __builtin_amdgcn_mfma_f32_16x16x32_bf16(a, bp[192], acc3, 0, 0, 0);
    }
    #pragma unroll
    for (int r = 0; r < 4; ++r) {
        long orow = band + lg * 4 + r;
        if (orow < M) {
            float dv = dinv[orow];
            out[orow * 64 +  0 + lr] = f2bf(acc0[r] * dv);
            out[orow * 64 + 16 + lr] = f2bf(acc1[r] * dv);
            out[orow * 64 + 32 + lr] = f2bf(acc2[r] * dv);
            out[orow * 64 + 48 + lr] = f2bf(acc3[r] * dv);
        }
    }
}

// ---------------- fused aggmm: h2out = bf16(dinv * (relu(agg(h2)+b1) @ W2)) --
// block = 256 thr = 4 waves = 16 nodes; quarter-wave per node, lane = 4 feats
__global__ __launch_bounds__(256) void aggmm_k(const unsigned short* __restrict__ h2,
                                               const unsigned short* __restrict__ wfrag2,
                                               unsigned short* __restrict__ hout,
                                               const int* __restrict__ rowptr,
                                               const int2* __restrict__ edges,
                                               const float* __restrict__ dinv,
                                               const float* __restrict__ bias, int N) {
    __shared__ unsigned short glds[16 * 64];
    int tid = threadIdx.x;
    int w = tid >> 6, l = tid & 63;
    int q = l >> 4, r = l & 15;
    int node = blockIdx.x * 16 + w * 4 + q;
    float a0 = 0.f, a1 = 0.f, a2 = 0.f, a3 = 0.f;
    if (node < N) {
        float di = dinv[node];
        ushort4 hv = *(const ushort4*)(h2 + (size_t)node * 64 + 4 * r);
        a0 = di * bf2f(hv.x); a1 = di * bf2f(hv.y);
        a2 = di * bf2f(hv.z); a3 = di * bf2f(hv.w);
        int s = rowptr[node], e = rowptr[node + 1];
        for (int base = s; base < e; base += 16) {
            int mm = e - base; mm = mm > 16 ? 16 : mm;
            int2 my = edges[base + (r < mm ? r : 0)];
            if (mm == 16) {
                #pragma unroll
                for (int j = 0; j < 16; ++j) {
                    int srcj = __shfl(my.x, j, 16);
                    float nj = __int_as_float(__shfl(my.y, j, 16));
                    ushort4 qv = *(const ushort4*)(h2 + (size_t)srcj * 64 + 4 * r);
                    a0 += nj * bf2f(qv.x); a1 += nj * bf2f(qv.y);
                    a2 += nj * bf2f(qv.z); a3 += nj * bf2f(qv.w);
                }
            } else {
                for (int j = 0; j < mm; ++j) {
                    int srcj = __shfl(my.x, j, 16);
                    float nj = __int_as_float(__shfl(my.y, j, 16));
                    ushort4 qv = *(const ushort4*)(h2 + (size_t)srcj * 64 + 4 * r);
                    a0 += nj * bf2f(qv.x); a1 += nj * bf2f(qv.y);
                    a2 += nj * bf2f(qv.z); a3 += nj * bf2f(qv.w);
                }
            }
        }
        float4 bb = *(const float4*)(bias + 4 * r);
        a0 = fmaxf(a0 + bb.x, 0.f); a1 = fmaxf(a1 + bb.y, 0.f);
        a2 = fmaxf(a2 + bb.z, 0.f); a3 = fmaxf(a3 + bb.w, 0.f);
    }
    ushort4 gv; gv.x = f2bf(a0); gv.y = f2bf(a1); gv.z = f2bf(a2); gv.w = f2bf(a3);
    *(ushort4*)&glds[(w * 4 + q) * 64 + 4 * r] = gv;
    __syncthreads();
    // MFMA: wave w computes col-block nf = w (cols w*16 .. w*16+15)
    f32x4 acc = {0.f, 0.f, 0.f, 0.f};
    #pragma unroll
    for (int kt = 0; kt < 2; ++kt) {
        bf16x8 afrag = *(const bf16x8*)&glds[(l & 15) * 64 + kt * 32 + (l >> 4) * 8];
        bf16x8 bfrag = *(const bf16x8*)&wfrag2[(size_t)((kt * 4 + w) * 64 + l) * 8];
        acc = __builtin_amdgcn_mfma_f32_16x16x32_bf16(afrag, bfrag, acc, 0, 0, 0);
    }
    #pragma unroll
    for (int rr = 0; rr < 4; ++rr) {
        int nrow = blockIdx.x * 16 + (l >> 4) * 4 + rr;
        if (nrow < N) {
            float dv = dinv[nrow];
            hout[(size_t)nrow * 64 + w * 16 + (l & 15)] = f2bf(acc[rr] * dv);
        }
    }
}

// ---------------- agg2f: quarter-wave per node (aggmm gather shape) ----------
// block = 256 thr = 4 waves = 16 nodes; lane r holds features 4r..4r+3
__global__ __launch_bounds__(256) void agg2f_k(const unsigned short* __restrict__ h2,
                                               const int* __restrict__ rowptr,
                                               const int2* __restrict__ edges,
                                               const float* __restrict__ dinv,
                                               const float* __restrict__ bias,
                                               const float* __restrict__ op,
                                               const float* __restrict__ M,
                                               const float* __restrict__ Wfc,
                                               const float* __restrict__ cvec,
                                               float* __restrict__ out, int N) {
    int tid = threadIdx.x;
    int w = tid >> 6, l = tid & 63;
    int q = l >> 4, r = l & 15;
    int node = blockIdx.x * 16 + w * 4 + q;
    if (node >= N) return;
    float di = dinv[node];
    ushort4 hv = *(const ushort4*)(h2 + (size_t)node * 64 + 4 * r);
    float a0 = di * bf2f(hv.x), a1 = di * bf2f(hv.y);
    float a2 = di * bf2f(hv.z), a3 = di * bf2f(hv.w);
    int s = rowptr[node], e = rowptr[node + 1];
    for (int base = s; base < e; base += 16) {
        int mm = e - base; mm = mm > 16 ? 16 : mm;
        int2 my = edges[base + (r < mm ? r : 0)];
        if (mm == 16) {
            #pragma unroll
            for (int j = 0; j < 16; ++j) {
                int srcj = __shfl(my.x, j, 16);
                float nj = __int_as_float(__shfl(my.y, j, 16));
                ushort4 qv = *(const ushort4*)(h2 + (size_t)srcj * 64 + 4 * r);
                a0 += nj * bf2f(qv.x); a1 += nj * bf2f(qv.y);
                a2 += nj * bf2f(qv.z); a3 += nj * bf2f(qv.w);
            }
        } else {
            for (int j = 0; j < mm; ++j) {
                int srcj = __shfl(my.x, j, 16);
                float nj = __int_as_float(__shfl(my.y, j, 16));
                ushort4 qv = *(const ushort4*)(h2 + (size_t)srcj * 64 + 4 * r);
                a0 += nj * bf2f(qv.x); a1 += nj * bf2f(qv.y);
                a2 += nj * bf2f(qv.z); a3 += nj * bf2f(qv.w);
            }
        }
    }
    float4 bb = *(const float4*)(bias + 4 * r);
    a0 = fmaxf(a0 + bb.x, 0.f); a1 = fmaxf(a1 + bb.y, 0.f);
    a2 = fmaxf(a2 + bb.z, 0.f); a3 = fmaxf(a3 + bb.w, 0.f);
    float4 ov = *(const float4*)(op + (size_t)node * 64 + 4 * r);
    int f = 4 * r;
    float p0 = a0 * M[(f+0)*2+0] + a1 * M[(f+1)*2+0] + a2 * M[(f+2)*2+0] + a3 * M[(f+3)*2+0]
             + ov.x * Wfc[(IN_C+f+0)*2+0] + ov.y * Wfc[(IN_C+f+1)*2+0]
             + ov.z * Wfc[(IN_C+f+2)*2+0] + ov.w * Wfc[(IN_C+f+3)*2+0];
    float p1 = a0 * M[(f+0)*2+1] + a1 * M[(f+1)*2+1] + a2 * M[(f+2)*2+1] + a3 * M[(f+3)*2+1]
             + ov.x * Wfc[(IN_C+f+0)*2+1] + ov.y * Wfc[(IN_C+f+1)*2+1]
             + ov.z * Wfc[(IN_C+f+2)*2+1] + ov.w * Wfc[(IN_C+f+3)*2+1];
    #pragma unroll
    for (int off = 8; off > 0; off >>= 1) {
        p0 += __shfl_xor(p0, off, 16);
        p1 += __shfl_xor(p1, off, 16);
    }
    if (r == 0)
        *(float2*)(out + (size_t)node * 2) = make_float2(p0 + cvec[0], p1 + cvec[1]);
}

extern "C" void kernel_launch(void* const* d_in, const int* in_sizes, int n_in,
                              void* d_out, int out_size, void* d_ws, size_t ws_size,
                              hipStream_t stream) {
    const float* x    = (const float*)d_in[0];
    const int*   ei   = (const int*)d_in[1];
    const float* attr = (const float*)d_in[2];
    const float* op   = (const float*)d_in[3];
    const float* W1   = (const float*)d_in[4];
    const float* b1   = (const float*)d_in[5];
    const float* W2   = (const float*)d_in[6];
    const float* b2   = (const float*)d_in[7];
    const float* Wp   = (const float*)d_in[8];
    const float* bp   = (const float*)d_in[9];
    const float* Wfc  = (const float*)d_in[10];
    const float* bfc  = (const float*)d_in[11];

    const int N = in_sizes[0] / IN_C;
    const int E = in_sizes[2];
    const int* row = ei;
    const int* col = ei + E;

    const int B     = (N + NPB - 1) >> NPB_SHIFT;
    const int nblk1 = (E + EPB - 1) / EPB;

    char* base = (char*)d_ws;
    size_t off = 0;
    auto alloc = [&](size_t bytes) -> char* {
        char* p = base + off;
        off = (off + bytes + 255) & ~(size_t)255;
        return p;
    };
    int2*  edges  = (int2*)alloc((size_t)E * 8);             // persistent CSR
    unsigned short* h2 = (unsigned short*)alloc((size_t)N * HID * 2); // layer-1 feats
    // region: binned u64 (E*8) dead after p2 -> later hout bf16 (N*64*2)
    size_t bin_b  = (size_t)E * 8;
    size_t g_b    = (size_t)N * HID * 2;
    char*  regC   = alloc(bin_b > g_b ? bin_b : g_b);
    unsigned long long* binned = (unsigned long long*)regC;
    unsigned short* hout = (unsigned short*)regC;
    int*   blkoff = (int*)alloc((size_t)nblk1 * B * 4);
    float* dinv   = (float*)alloc((size_t)N * 4);
    int*   rowptr = (int*)alloc((size_t)(N + 1) * 4);
    int*   gcnt   = (int*)alloc((size_t)MAXB * 4);
    int*   bptr   = (int*)alloc((size_t)(MAXB + 1) * 4);
    unsigned short* wfrag1 = (unsigned short*)alloc((size_t)IN_C * 64 * 2);  // 64KB
    unsigned short* wfrag2 = (unsigned short*)alloc((size_t)HID * 64 * 2);   // 8KB
    float* Mbuf   = (float*)alloc(512);
    float* cvec   = (float*)alloc(64);

    const int gGemm  = (N + 127) / 128;
    const int gAggmm = (N + 15) / 16;
    const int gSetup = 145 + (B + 255) / 256;

    setup_k<<<gSetup, 256, 0, stream>>>(Wp, bp, Wfc, bfc, Mbuf, cvec,
                                        W1, wfrag1, W2, wfrag2, gcnt, B);
    p1a_k<<<nblk1, BINB, 0, stream>>>(col, gcnt, blkoff, E, B);
    p1b_k<<<nblk1, BINB, 0, stream>>>(row, col, attr, blkoff, gcnt, bptr, binned, E, B);
    p2_k<<<B, 256, 0, stream>>>(binned, bptr, edges, rowptr, dinv, N, E);

    // conv1: h2 = bf16(dinv * (x @ W1)) via MFMA
    gemm1_k<<<gGemm, 512, 0, stream>>>(x, wfrag1, dinv, h2, N);
    // conv2 first half fused: hout = bf16(dinv * (relu(agg(h2)+b1) @ W2))
    aggmm_k<<<gAggmm, 256, 0, stream>>>(h2, wfrag2, hout, rowptr, edges, dinv, b1, N);
    // layer-2 agg + fused final projection (quarter-wave gather shape)
    agg2f_k<<<gAggmm, 256, 0, stream>>>(hout, rowptr, edges, dinv, b2, op, Mbuf, Wfc, cvec,
                                        (float*)d_out, N);
}